// Round 15
// baseline (37.136 us; speedup 1.0000x reference)
//
#include <hip/hip_runtime.h>
#include <math.h>

#define N_NODES 65536
#define G_SEG   512
#define NE      256                  // L-grid intervals over [0,10] for xw lerp

// K1 roles
#define NB_HS 33                     // hs table 257x32
#define NB_Q  128                    // Q[z][m][j]: block = (m, z-quarter)
#define NB_QM 32                     // Qm[mo][m][j]: block = m
#define NB_S  3                      // seg bounds
#define NB_P0 (N_NODES / 256)        // 256: per-node aux
#define NB_K1 (NB_HS + NB_Q + NB_QM + NB_S + NB_P0)   // 452

// K2 roles
#define NB_A  1700                   // 17 e-tiles x 100 z
#define NB_B2 257                    // B rows
#define NB_K2 (NB_A + NB_B2)

#define AP_ELEMS (256 * 100 * 128)   // packed lerp pairs, 13.1 MB
#define BP_ELEMS (256 * 3 * 128)     // 393 KB
#define Q_ELEMS  (100 * 32 * 64)     // 800 KB
#define QM_ELEMS (3 * 32 * 64)
#define HS_ELEMS (257 * 32)

// ---------------------------------------------------------------------------
// K1: five independent light roles.  (unchanged from round 13/14)
// ---------------------------------------------------------------------------
__global__ __launch_bounds__(256) void prep1(
    const float* __restrict__ emb_z, const float* __restrict__ emb_mol,
    const float* __restrict__ W2, const float* __restrict__ W1,
    const int* __restrict__ batch,
    const float* __restrict__ pos, const int* __restrict__ xz,
    const int* __restrict__ mol,
    float* __restrict__ Q, float* __restrict__ Qm, float* __restrict__ hs,
    int* __restrict__ seg, float4* __restrict__ aux, float silu_c)
{
    __shared__ float w2s[64 * 49];   // [cc][u], stride 49 kills bank conflicts
    __shared__ float ezq[1200];      // 25 z x 48 u

    const int b = blockIdx.x;
    const int t = threadIdx.x;

    if (b < NB_HS) {
        const int tid = b * 256 + t;
        if (tid >= HS_ELEMS) return;
        const int e = tid >> 5, m = tid & 31;
        const float L = (float)e * (10.f / (float)NE);
        const float c = 8.4335412f;     // 1.14136 * exp(2)
        float p = 0.f;
#pragma unroll
        for (int k = 0; k < 10; ++k) {
            const float a  = 1.1f * L - (float)k;
            const float bb = (float)(k + 2) - 1.1f * L;
            // exp(-1/a)*exp(-1/b) = exp(-2/(ab)) since a+b == 2
            const float bas = (a > 0.f && bb > 0.f) ? c * __expf(-2.f / (a * bb)) : 0.f;
            p = fmaf(bas, W1[k * 32 + m], p);
        }
        const float scale = 0.02209708691207961f;   // 1/sqrt(2048), folded here
        hs[tid] = scale * silu_c * p / (1.f + __expf(-p));
    } else if (b < NB_HS + NB_Q) {
        const int q  = b - NB_HS;
        const int m  = q >> 2;
        const int zq = q & 3;
        for (int p = t; p < 3072; p += 256) {
            const int l = p / 768, r = p - l * 768;       // r = u*16+wi, u<48
            w2s[((l * 16) + (r & 15)) * 49 + (r >> 4)] = W2[m * 4096 + l * 1024 + r];
        }
        for (int p = t; p < 1200; p += 256) ezq[p] = emb_z[zq * 1200 + p];
        __syncthreads();

        const int zg = t >> 6, cc = t & 63;
#pragma unroll
        for (int zi = 0; zi < 7; ++zi) {
            const int zl = zg + 4 * zi;                   // wave-uniform
            if (zl < 25) {
                float a0 = 0.f, a1 = 0.f, a2 = 0.f, a3 = 0.f;
#pragma unroll
                for (int u = 0; u < 48; u += 4) {
                    a0 = fmaf(ezq[zl * 48 + u + 0], w2s[cc * 49 + u + 0], a0);
                    a1 = fmaf(ezq[zl * 48 + u + 1], w2s[cc * 49 + u + 1], a1);
                    a2 = fmaf(ezq[zl * 48 + u + 2], w2s[cc * 49 + u + 2], a2);
                    a3 = fmaf(ezq[zl * 48 + u + 3], w2s[cc * 49 + u + 3], a3);
                }
                Q[(((zq * 25 + zl) * 32 + m) << 6) + cc] = (a0 + a1) + (a2 + a3);
            }
        }
    } else if (b < NB_HS + NB_Q + NB_QM) {
        const int m = b - (NB_HS + NB_Q);
        if (t < 192) {
            const int mo = t >> 6, j = t & 63;
            const float* wp = W2 + m * 4096 + (j >> 4) * 1024 + 768 + (j & 15);
            float acc = 0.f;
#pragma unroll
            for (int v = 0; v < 16; ++v)
                acc = fmaf(emb_mol[mo * 16 + v], wp[v * 16], acc);
            Qm[((mo * 32 + m) << 6) + j] = acc;
        }
    } else if (b < NB_HS + NB_Q + NB_QM + NB_S) {
        const int g = (b - NB_HS - NB_Q - NB_QM) * 256 + t;
        if (g > G_SEG) return;
        int lo = 0, hi = N_NODES;
        while (lo < hi) {
            const int mid = (lo + hi) >> 1;
            if (batch[mid] < g) lo = mid + 1; else hi = mid;
        }
        seg[g] = lo;
    } else {
        const int i = (b - NB_HS - NB_Q - NB_QM - NB_S) * 256 + t;
        const float px = pos[3 * i], py = pos[3 * i + 1], pz = pos[3 * i + 2];
        const int z  = xz[i];
        const int mo = mol[i];
        const float Lsq = px * px + py * py + pz * pz;
        const float rinv = __builtin_amdgcn_rsqf(Lsq);
        const float L = Lsq * rinv;
        const float tt = fminf(L * ((float)NE / 10.0f), 255.999f);
        const int e = (int)tt;
        const int fr15 = min((int)((tt - (float)e) * 32768.f), 32767);
        float4 a;
        a.x = px * rinv; a.y = py * rinv; a.z = pz * rinv;
        a.w = __uint_as_float(((unsigned)e << 24) | ((unsigned)z << 17) |
                              ((unsigned)mo << 15) | (unsigned)fr15);
        aux[i] = a;
    }
}

// ---------------------------------------------------------------------------
// K2: value v(e,z,j) = sum_m hs[e][m]*Q[z][m][j] is stored PACKED for lerp:
//   e < 256:  AP[e][z][2j]   = v   (the "f0" slot of bin e)
//   e > 0:    AP[e-1][z][2j+1] = v (the "f1" slot of bin e-1)
// Same for B via Qm. One float2 load then yields both lerp endpoints.
// ---------------------------------------------------------------------------
__global__ __launch_bounds__(256) void build_AB2(
    const float* __restrict__ Q, const float* __restrict__ Qm,
    const float* __restrict__ hs,
    float* __restrict__ AP, float* __restrict__ BP)
{
    const int b = blockIdx.x;
    const int t = threadIdx.x;
    const int j = t & 63;
    const int er = __builtin_amdgcn_readfirstlane(t >> 6);

    if (b < NB_A) {
        const int et = b / 100;
        const int z  = b - et * 100;
        float Qr[32];
        const float* Qp = Q + ((z * 32) << 6) + j;
#pragma unroll
        for (int m = 0; m < 32; ++m) Qr[m] = Qp[m << 6];

        const int e0 = et * 16;
#pragma unroll
        for (int p4 = 0; p4 < 4; ++p4) {
            const int e = e0 + er + 4 * p4;               // wave-uniform
            if (e < 257) {
                const float* hp = hs + e * 32;
                float a0 = 0.f, a1 = 0.f, a2 = 0.f, a3 = 0.f;
#pragma unroll
                for (int m = 0; m < 32; m += 4) {
                    a0 = fmaf(hp[m + 0], Qr[m + 0], a0);
                    a1 = fmaf(hp[m + 1], Qr[m + 1], a1);
                    a2 = fmaf(hp[m + 2], Qr[m + 2], a2);
                    a3 = fmaf(hp[m + 3], Qr[m + 3], a3);
                }
                const float v = (a0 + a1) + (a2 + a3);
                if (e < 256) AP[((e * 100 + z) << 7) + 2 * j] = v;
                if (e > 0)   AP[(((e - 1) * 100 + z) << 7) + 2 * j + 1] = v;
            }
        }
    } else {
        const int e  = b - NB_A;                          // 0..256
        const int mo = t >> 6;
        if (mo < 3) {
            const float* Qp = Qm + ((mo * 32) << 6) + j;
            const float* hp = hs + e * 32;
            float acc = 0.f;
#pragma unroll
            for (int m = 0; m < 32; ++m)
                acc = fmaf(hp[m], Qp[m << 6], acc);
            if (e < 256) BP[((e * 3 + mo) << 7) + 2 * j] = acc;
            if (e > 0)   BP[(((e - 1) * 3 + mo) << 7) + 2 * j + 1] = acc;
        }
    }
}

// ---------------------------------------------------------------------------
// K3: one block per segment, 1024 thr = 16 waves. Wave w: l = w&3, qt = w>>2.
// lane = ns*16+wi covers 4 nodes/iter. Per node per lane: ONE float2 AP load
// + ONE float2 BP load (packed lerp endpoints). Software pipeline: aux 2-deep,
// rows 1-deep, issued before the compute they hide under. Direct mean write.
// ---------------------------------------------------------------------------
__global__ __launch_bounds__(1024) void seg_mean(
    const float4* __restrict__ aux, const int* __restrict__ seg,
    const float2* __restrict__ AP2, const float2* __restrict__ BP2,
    float* __restrict__ out)
{
    __shared__ float red[16 * 257];

    const int g  = blockIdx.x;
    const int s0 = seg[g], s1 = seg[g + 1];
    const int cnt = s1 - s0;

    const int w16  = __builtin_amdgcn_readfirstlane(threadIdx.x >> 6);  // 0..15
    const int l    = w16 & 3;
    const int qt   = w16 >> 2;
    const int lane = threadIdx.x & 63;
    const int ns   = lane >> 4;
    const int wi   = lane & 15;
    const int jj   = l * 16 + wi;

    const int q0 = s0 + ((cnt * qt) >> 2);
    const int q1 = s0 + ((cnt * (qt + 1)) >> 2);

    float acc[7];
#pragma unroll
    for (int k = 0; k < 7; ++k) acc[k] = 0.f;

    const int niter = (q1 - q0 + 3) >> 2;   // wave-uniform

    float4 axC = make_float4(0.f, 0.f, 1.f, __uint_as_float(0u));
    float4 axN = axC;
    float2 avC = make_float2(0.f, 0.f), bvC = avC;

    if (niter > 0) axC = aux[min(q0 + ns, q1 - 1)];
    if (niter > 1) axN = aux[min(q0 + 4 + ns, q1 - 1)];
    if (niter > 0) {
        const unsigned cd = __float_as_uint(axC.w);
        avC = AP2[((cd >> 24) * 100 + ((cd >> 17) & 127u)) * 64 + jj];
        bvC = BP2[((cd >> 24) * 3 + ((cd >> 15) & 3u)) * 64 + jj];
    }

    for (int it = 0; it < niter; ++it) {
        // issue next rows + aux(it+2) BEFORE the compute that hides them
        float2 avN = avC, bvN = bvC;
        float4 axNN = axN;
        if (it + 1 < niter) {
            const unsigned cn = __float_as_uint(axN.w);
            avN = AP2[((cn >> 24) * 100 + ((cn >> 17) & 127u)) * 64 + jj];
            bvN = BP2[((cn >> 24) * 3 + ((cn >> 15) & 3u)) * 64 + jj];
        }
        if (it + 2 < niter)
            axNN = aux[min(q0 + (it + 2) * 4 + ns, q1 - 1)];

        // compute iteration it
        const unsigned code = __float_as_uint(axC.w);
        const int i = q0 + it * 4 + ns;
        const bool valid = (i < q1);
        const float fr = (float)(code & 32767u) * 3.0517578125e-5f;  // /32768
        const float f0 = avC.x + bvC.x, f1 = avC.y + bvC.y;
        float xwv = fmaf(fr, f1 - f0, f0);
        xwv = valid ? xwv : 0.f;

        const float ux = axC.x, uy = axC.y, uz = axC.z;
        const float s3 = 1.7320508075688772f, s5 = 2.2360679774997896f, s7 = 2.6457513110645907f;

        if (l == 0) {
            acc[0] += xwv;
        } else if (l == 1) {
            acc[0] = fmaf(xwv, s3 * ux, acc[0]);
            acc[1] = fmaf(xwv, s3 * uy, acc[1]);
            acc[2] = fmaf(xwv, s3 * uz, acc[2]);
        } else if (l == 2) {
            const float y2 = uy * uy, x2z2 = ux * ux + uz * uz;
            const float s20 = s3 * ux * uz;
            const float s21 = s3 * ux * uy;
            const float s22 = y2 - 0.5f * x2z2;
            const float s23 = s3 * uy * uz;
            const float s24 = 0.5f * s3 * (uz * uz - ux * ux);
            const float xs = xwv * s5;
            acc[0] = fmaf(xs, s20, acc[0]);
            acc[1] = fmaf(xs, s21, acc[1]);
            acc[2] = fmaf(xs, s22, acc[2]);
            acc[3] = fmaf(xs, s23, acc[3]);
            acc[4] = fmaf(xs, s24, acc[4]);
        } else {
            const float y2 = uy * uy, x2z2 = ux * ux + uz * uz;
            const float s20 = s3 * ux * uz;
            const float s24 = 0.5f * s3 * (uz * uz - ux * ux);
            const float c56 = 0.9128709291752769f;  // sqrt(5/6)
            const float c38 = 0.6123724356957945f;  // sqrt(3/8)
            const float r4 = 4.f * y2 - x2z2;
            const float s30 = c56 * (s20 * uz + s24 * ux);
            const float s31 = s5 * s20 * uy;
            const float s32 = c38 * r4 * ux;
            const float s33 = 0.5f * uy * (2.f * y2 - 3.f * x2z2);
            const float s34 = c38 * uz * r4;
            const float s35 = s5 * s24 * uy;
            const float s36 = c56 * (s24 * uz - s20 * ux);
            const float xs = xwv * s7;
            acc[0] = fmaf(xs, s30, acc[0]);
            acc[1] = fmaf(xs, s31, acc[1]);
            acc[2] = fmaf(xs, s32, acc[2]);
            acc[3] = fmaf(xs, s33, acc[3]);
            acc[4] = fmaf(xs, s34, acc[4]);
            acc[5] = fmaf(xs, s35, acc[5]);
            acc[6] = fmaf(xs, s36, acc[6]);
        }

        axC = axN; axN = axNN; avC = avN; bvC = bvN;
    }

    const int nl = 2 * l + 1;
    const int off = (l == 0 ? 0 : (l == 1 ? 16 : (l == 2 ? 64 : 144)));
    const int base = off + wi * nl;
#pragma unroll
    for (int k = 0; k < 7; ++k)
        if (k < nl) red[(qt * 4 + ns) * 257 + base + k] = acc[k];
    __syncthreads();

    if (threadIdx.x < 256) {
        float s = 0.f;
#pragma unroll
        for (int ww = 0; ww < 16; ++ww) s += red[ww * 257 + threadIdx.x];
        out[g * 256 + threadIdx.x] = s / (float)max(cnt, 1);
    }
}

// ---------------------------------------------------------------------------
static double silu_c_host()
{
    const int n = 200001;
    const double h = 24.0 / 200000.0;
    double sum = 0.0, prev = 0.0;
    for (int i = 0; i < n; ++i) {
        const double z = -12.0 + h * (double)i;
        const double pdf = exp(-0.5 * z * z) * 0.3989422804014327;
        const double s = z / (1.0 + exp(-z));
        const double f = s * s * pdf;
        if (i) sum += prev + f;
        prev = f;
    }
    sum *= 0.5 * h;
    return 1.0 / sqrt(sum);
}

extern "C" void kernel_launch(void* const* d_in, const int* in_sizes, int n_in,
                              void* d_out, int out_size, void* d_ws, size_t ws_size,
                              hipStream_t stream)
{
    const float* pos     = (const float*)d_in[0];
    const int*   xz      = (const int*)d_in[1];
    const int*   mol     = (const int*)d_in[2];
    const int*   batch   = (const int*)d_in[3];
    const float* emb_z   = (const float*)d_in[4];
    const float* emb_mol = (const float*)d_in[5];
    const float* W1      = (const float*)d_in[6];
    const float* W2      = (const float*)d_in[7];
    float* out = (float*)d_out;

    // workspace (floats): aux | AP | BP | Q | Qm | hs | seg ~= 15.5 MB
    float4* aux  = (float4*)d_ws;
    float*  APb  = (float*)d_ws + 4 * N_NODES;
    float*  BPb  = APb + AP_ELEMS;
    float*  Qbuf = BPb + BP_ELEMS;
    float*  Qmb  = Qbuf + Q_ELEMS;
    float*  hsb  = Qmb + QM_ELEMS;
    int*    seg  = (int*)(hsb + HS_ELEMS);

    static const float SILU_C_F = (float)silu_c_host();

    prep1<<<NB_K1, 256, 0, stream>>>(emb_z, emb_mol, W2, W1, batch,
                                     pos, xz, mol, Qbuf, Qmb, hsb, seg, aux, SILU_C_F);
    build_AB2<<<NB_K2, 256, 0, stream>>>(Qbuf, Qmb, hsb, APb, BPb);
    seg_mean<<<G_SEG, 1024, 0, stream>>>(aux, seg, (const float2*)APb,
                                         (const float2*)BPb, out);
}

// Round 16
// 34.403 us; speedup vs baseline: 1.0794x; 1.0794x over previous
//
#include <hip/hip_runtime.h>
#include <math.h>

#define N_NODES 65536
#define G_SEG   512
#define NE      256                  // L-grid intervals over [0,10] for xw lerp

// K1 roles
#define NB_HS 33                     // hs table 257x32
#define NB_Q  128                    // Q[z][m][j]: block = (m, z-quarter)
#define NB_QM 32                     // Qm[mo][m][j]: block = m
#define NB_S  3                      // seg bounds
#define NB_P0 (N_NODES / 256)        // 256: per-node aux
#define NB_K1 (NB_HS + NB_Q + NB_QM + NB_S + NB_P0)   // 452

// K2 roles
#define NB_A  1700                   // 17 e-tiles x 100 z
#define NB_B2 257                    // B rows
#define NB_K2 (NB_A + NB_B2)

#define A_ELEMS  (257 * 100 * 64)    // 6.58 MB
#define B_ELEMS  (257 * 3 * 64)
#define Q_ELEMS  (100 * 32 * 64)     // 800 KB
#define QM_ELEMS (3 * 32 * 64)
#define HS_ELEMS (257 * 32)

// ---------------------------------------------------------------------------
// K1: five independent light roles. Q-role: div-free staging + W2 row hoisted
// to registers (reused across 7 z-iterations).
// ---------------------------------------------------------------------------
__global__ __launch_bounds__(256) void prep1(
    const float* __restrict__ emb_z, const float* __restrict__ emb_mol,
    const float* __restrict__ W2, const float* __restrict__ W1,
    const int* __restrict__ batch,
    const float* __restrict__ pos, const int* __restrict__ xz,
    const int* __restrict__ mol,
    float* __restrict__ Q, float* __restrict__ Qm, float* __restrict__ hs,
    int* __restrict__ seg, float4* __restrict__ aux, float silu_c)
{
    __shared__ float w2s[64 * 49];   // [cc][u], stride 49 kills bank conflicts
    __shared__ float ezq[1200];      // 25 z x 48 u

    const int b = blockIdx.x;
    const int t = threadIdx.x;

    if (b < NB_HS) {
        const int tid = b * 256 + t;
        if (tid >= HS_ELEMS) return;
        const int e = tid >> 5, m = tid & 31;
        const float L = (float)e * (10.f / (float)NE);
        const float c = 8.4335412f;     // 1.14136 * exp(2)
        float p = 0.f;
#pragma unroll
        for (int k = 0; k < 10; ++k) {
            const float a  = 1.1f * L - (float)k;
            const float bb = (float)(k + 2) - 1.1f * L;
            // exp(-1/a)*exp(-1/b) = exp(-2/(ab)) since a+b == 2
            const float bas = (a > 0.f && bb > 0.f) ? c * __expf(-2.f / (a * bb)) : 0.f;
            p = fmaf(bas, W1[k * 32 + m], p);
        }
        const float scale = 0.02209708691207961f;   // 1/sqrt(2048), folded here
        hs[tid] = scale * silu_c * p / (1.f + __expf(-p));
    } else if (b < NB_HS + NB_Q) {
        const int q  = b - NB_HS;
        const int m  = q >> 2;
        const int zq = q & 3;
        // div-free staging: w2s[(l*16 + (r&15))*49 + (r>>4)] = W2[m*4096+l*1024+r]
#pragma unroll
        for (int l = 0; l < 4; ++l)
            for (int r = t; r < 768; r += 256)
                w2s[((l * 16) + (r & 15)) * 49 + (r >> 4)] = W2[m * 4096 + l * 1024 + r];
        for (int p = t; p < 1200; p += 256) ezq[p] = emb_z[zq * 1200 + p];
        __syncthreads();

        const int zg = t >> 6, cc = t & 63;
        float wr[48];                    // thread's W2 column, reused 7x
#pragma unroll
        for (int u = 0; u < 48; ++u) wr[u] = w2s[cc * 49 + u];
#pragma unroll
        for (int zi = 0; zi < 7; ++zi) {
            const int zl = zg + 4 * zi;                   // wave-uniform
            if (zl < 25) {
                float a0 = 0.f, a1 = 0.f, a2 = 0.f, a3 = 0.f;
#pragma unroll
                for (int u = 0; u < 48; u += 4) {
                    a0 = fmaf(ezq[zl * 48 + u + 0], wr[u + 0], a0);
                    a1 = fmaf(ezq[zl * 48 + u + 1], wr[u + 1], a1);
                    a2 = fmaf(ezq[zl * 48 + u + 2], wr[u + 2], a2);
                    a3 = fmaf(ezq[zl * 48 + u + 3], wr[u + 3], a3);
                }
                Q[(((zq * 25 + zl) * 32 + m) << 6) + cc] = (a0 + a1) + (a2 + a3);
            }
        }
    } else if (b < NB_HS + NB_Q + NB_QM) {
        const int m = b - (NB_HS + NB_Q);
        if (t < 192) {
            const int mo = t >> 6, j = t & 63;
            const float* wp = W2 + m * 4096 + (j >> 4) * 1024 + 768 + (j & 15);
            float acc = 0.f;
#pragma unroll
            for (int v = 0; v < 16; ++v)
                acc = fmaf(emb_mol[mo * 16 + v], wp[v * 16], acc);
            Qm[((mo * 32 + m) << 6) + j] = acc;
        }
    } else if (b < NB_HS + NB_Q + NB_QM + NB_S) {
        const int g = (b - NB_HS - NB_Q - NB_QM) * 256 + t;
        if (g > G_SEG) return;
        int lo = 0, hi = N_NODES;
        while (lo < hi) {
            const int mid = (lo + hi) >> 1;
            if (batch[mid] < g) lo = mid + 1; else hi = mid;
        }
        seg[g] = lo;
    } else {
        const int i = (b - NB_HS - NB_Q - NB_QM - NB_S) * 256 + t;
        const float px = pos[3 * i], py = pos[3 * i + 1], pz = pos[3 * i + 2];
        const int z  = xz[i];
        const int mo = mol[i];
        const float Lsq = px * px + py * py + pz * pz;
        const float rinv = __builtin_amdgcn_rsqf(Lsq);
        const float L = Lsq * rinv;
        const float tt = fminf(L * ((float)NE / 10.0f), 255.999f);
        const int e = (int)tt;
        const int fr15 = min((int)((tt - (float)e) * 32768.f), 32767);
        float4 a;
        a.x = px * rinv; a.y = py * rinv; a.z = pz * rinv;
        a.w = __uint_as_float(((unsigned)e << 24) | ((unsigned)z << 17) |
                              ((unsigned)mo << 15) | (unsigned)fr15);
        aux[i] = a;
    }
}

// ---------------------------------------------------------------------------
// K2: A[e][z][j] = sum_m hs[e][m] * Q[z][m][j]. The 8 KB Q-row is staged
// coalesced (float4) into padded LDS [32][65] once per block, then each
// thread pulls its 32-value column via conflict-free LDS reads (<=2-way).
// Replaces 32 stride-256B L2 dword loads per thread.
// ---------------------------------------------------------------------------
__global__ __launch_bounds__(256) void build_AB2(
    const float* __restrict__ Q, const float* __restrict__ Qm,
    const float* __restrict__ hs,
    float* __restrict__ A, float* __restrict__ B)
{
    __shared__ float qs[32 * 65];

    const int b = blockIdx.x;
    const int t = threadIdx.x;
    const int j = t & 63;
    const int er = __builtin_amdgcn_readfirstlane(t >> 6);

    if (b < NB_A) {
        const int et = b / 100;
        const int z  = b - et * 100;

        // stage Q[z] (2048 dwords) coalesced
        const float4* Qsrc = reinterpret_cast<const float4*>(Q + ((z * 32) << 6));
#pragma unroll
        for (int p = t; p < 512; p += 256) {
            const float4 v = Qsrc[p];
            const int base = p << 2;               // dword index: m*64 + j4
            const int mm = base >> 6, j4 = base & 63;
            qs[mm * 65 + j4 + 0] = v.x;
            qs[mm * 65 + j4 + 1] = v.y;
            qs[mm * 65 + j4 + 2] = v.z;
            qs[mm * 65 + j4 + 3] = v.w;
        }
        __syncthreads();

        float Qr[32];
#pragma unroll
        for (int m = 0; m < 32; ++m) Qr[m] = qs[m * 65 + j];

        const int e0 = et * 16;
#pragma unroll
        for (int p4 = 0; p4 < 4; ++p4) {
            const int e = e0 + er + 4 * p4;               // wave-uniform
            if (e < 257) {
                const float* hp = hs + e * 32;
                float a0 = 0.f, a1 = 0.f, a2 = 0.f, a3 = 0.f;
#pragma unroll
                for (int m = 0; m < 32; m += 4) {
                    a0 = fmaf(hp[m + 0], Qr[m + 0], a0);
                    a1 = fmaf(hp[m + 1], Qr[m + 1], a1);
                    a2 = fmaf(hp[m + 2], Qr[m + 2], a2);
                    a3 = fmaf(hp[m + 3], Qr[m + 3], a3);
                }
                A[((e * 100 + z) << 6) + j] = (a0 + a1) + (a2 + a3);
            }
        }
    } else {
        const int e  = b - NB_A;
        const int mo = t >> 6;
        if (mo < 3) {
            const float* Qp = Qm + ((mo * 32) << 6) + j;
            const float* hp = hs + e * 32;
            float acc = 0.f;
#pragma unroll
            for (int m = 0; m < 32; ++m)
                acc = fmaf(hp[m], Qp[m << 6], acc);
            B[((e * 3 + mo) << 6) + j] = acc;
        }
    }
}

// ---------------------------------------------------------------------------
// K3: EXACT round-14 seg_mean. One block per segment, 1024 thr = 16 waves.
// Wave w: l = w&3 (wave-uniform SH), qt = w>>2 (node-quarter). lane = ns*16+wi
// covers 4 nodes/iter. red[16][257]: row = qt*4+ns; the four l-waves write
// disjoint column ranges. Direct mean write -- no partials/reduce/atomics.
// ---------------------------------------------------------------------------
__global__ __launch_bounds__(1024) void seg_mean(
    const float4* __restrict__ aux, const int* __restrict__ seg,
    const float* __restrict__ A, const float* __restrict__ B,
    float* __restrict__ out)
{
    __shared__ float red[16 * 257];

    const int g  = blockIdx.x;
    const int s0 = seg[g], s1 = seg[g + 1];
    const int cnt = s1 - s0;

    const int w16  = __builtin_amdgcn_readfirstlane(threadIdx.x >> 6);  // 0..15
    const int l    = w16 & 3;
    const int qt   = w16 >> 2;
    const int lane = threadIdx.x & 63;
    const int ns   = lane >> 4;
    const int wi   = lane & 15;
    const int jj   = l * 16 + wi;

    const int q0 = s0 + ((cnt * qt) >> 2);
    const int q1 = s0 + ((cnt * (qt + 1)) >> 2);

    float acc[7];
#pragma unroll
    for (int k = 0; k < 7; ++k) acc[k] = 0.f;

    const int niter = (q1 - q0 + 3) >> 2;   // wave-uniform

    float4 aN = make_float4(0.f, 0.f, 1.f, __uint_as_float(0u));
    float a0N = 0.f, a1N = 0.f, b0N = 0.f, b1N = 0.f;
    if (niter > 0) {
        const int ic = min(q0 + ns, q1 - 1);
        aN = aux[ic];
        const unsigned cd = __float_as_uint(aN.w);
        const float* Ar = A + (((cd >> 24) * 100 + ((cd >> 17) & 127u)) << 6) + jj;
        const float* Br = B + (((cd >> 24) * 3 + ((cd >> 15) & 3u)) << 6) + jj;
        a0N = Ar[0]; a1N = Ar[6400]; b0N = Br[0]; b1N = Br[192];
    }

    for (int it = 0; it < niter; ++it) {
        const float4 a = aN;
        const float f0 = a0N + b0N, f1 = a1N + b1N;
        const unsigned code = __float_as_uint(a.w);
        const int i = q0 + it * 4 + ns;
        const bool valid = (i < q1);

        if (it + 1 < niter) {
            const int ic = min(q0 + (it + 1) * 4 + ns, q1 - 1);
            aN = aux[ic];
            const unsigned cn = __float_as_uint(aN.w);
            const float* Ar = A + (((cn >> 24) * 100 + ((cn >> 17) & 127u)) << 6) + jj;
            const float* Br = B + (((cn >> 24) * 3 + ((cn >> 15) & 3u)) << 6) + jj;
            a0N = Ar[0]; a1N = Ar[6400]; b0N = Br[0]; b1N = Br[192];
        }

        const float fr = (float)(code & 32767u) * 3.0517578125e-5f;  // /32768
        float xwv = fmaf(fr, f1 - f0, f0);
        xwv = valid ? xwv : 0.f;

        const float ux = a.x, uy = a.y, uz = a.z;
        const float s3 = 1.7320508075688772f, s5 = 2.2360679774997896f, s7 = 2.6457513110645907f;

        if (l == 0) {
            acc[0] += xwv;
        } else if (l == 1) {
            acc[0] = fmaf(xwv, s3 * ux, acc[0]);
            acc[1] = fmaf(xwv, s3 * uy, acc[1]);
            acc[2] = fmaf(xwv, s3 * uz, acc[2]);
        } else if (l == 2) {
            const float y2 = uy * uy, x2z2 = ux * ux + uz * uz;
            const float s20 = s3 * ux * uz;
            const float s21 = s3 * ux * uy;
            const float s22 = y2 - 0.5f * x2z2;
            const float s23 = s3 * uy * uz;
            const float s24 = 0.5f * s3 * (uz * uz - ux * ux);
            const float xs = xwv * s5;
            acc[0] = fmaf(xs, s20, acc[0]);
            acc[1] = fmaf(xs, s21, acc[1]);
            acc[2] = fmaf(xs, s22, acc[2]);
            acc[3] = fmaf(xs, s23, acc[3]);
            acc[4] = fmaf(xs, s24, acc[4]);
        } else {
            const float y2 = uy * uy, x2z2 = ux * ux + uz * uz;
            const float s20 = s3 * ux * uz;
            const float s24 = 0.5f * s3 * (uz * uz - ux * ux);
            const float c56 = 0.9128709291752769f;  // sqrt(5/6)
            const float c38 = 0.6123724356957945f;  // sqrt(3/8)
            const float r4 = 4.f * y2 - x2z2;
            const float s30 = c56 * (s20 * uz + s24 * ux);
            const float s31 = s5 * s20 * uy;
            const float s32 = c38 * r4 * ux;
            const float s33 = 0.5f * uy * (2.f * y2 - 3.f * x2z2);
            const float s34 = c38 * uz * r4;
            const float s35 = s5 * s24 * uy;
            const float s36 = c56 * (s24 * uz - s20 * ux);
            const float xs = xwv * s7;
            acc[0] = fmaf(xs, s30, acc[0]);
            acc[1] = fmaf(xs, s31, acc[1]);
            acc[2] = fmaf(xs, s32, acc[2]);
            acc[3] = fmaf(xs, s33, acc[3]);
            acc[4] = fmaf(xs, s34, acc[4]);
            acc[5] = fmaf(xs, s35, acc[5]);
            acc[6] = fmaf(xs, s36, acc[6]);
        }
    }

    const int nl = 2 * l + 1;
    const int off = (l == 0 ? 0 : (l == 1 ? 16 : (l == 2 ? 64 : 144)));
    const int base = off + wi * nl;
#pragma unroll
    for (int k = 0; k < 7; ++k)
        if (k < nl) red[(qt * 4 + ns) * 257 + base + k] = acc[k];
    __syncthreads();

    if (threadIdx.x < 256) {
        float s = 0.f;
#pragma unroll
        for (int ww = 0; ww < 16; ++ww) s += red[ww * 257 + threadIdx.x];
        out[g * 256 + threadIdx.x] = s / (float)max(cnt, 1);
    }
}

// ---------------------------------------------------------------------------
static double silu_c_host()
{
    const int n = 200001;
    const double h = 24.0 / 200000.0;
    double sum = 0.0, prev = 0.0;
    for (int i = 0; i < n; ++i) {
        const double z = -12.0 + h * (double)i;
        const double pdf = exp(-0.5 * z * z) * 0.3989422804014327;
        const double s = z / (1.0 + exp(-z));
        const double f = s * s * pdf;
        if (i) sum += prev + f;
        prev = f;
    }
    sum *= 0.5 * h;
    return 1.0 / sqrt(sum);
}

extern "C" void kernel_launch(void* const* d_in, const int* in_sizes, int n_in,
                              void* d_out, int out_size, void* d_ws, size_t ws_size,
                              hipStream_t stream)
{
    const float* pos     = (const float*)d_in[0];
    const int*   xz      = (const int*)d_in[1];
    const int*   mol     = (const int*)d_in[2];
    const int*   batch   = (const int*)d_in[3];
    const float* emb_z   = (const float*)d_in[4];
    const float* emb_mol = (const float*)d_in[5];
    const float* W1      = (const float*)d_in[6];
    const float* W2      = (const float*)d_in[7];
    float* out = (float*)d_out;

    // workspace (floats): aux | A | B | Q | Qm | hs | seg  ~= 8.7 MB
    float4* aux  = (float4*)d_ws;
    float*  Abuf = (float*)d_ws + 4 * N_NODES;
    float*  Bbuf = Abuf + A_ELEMS;
    float*  Qbuf = Bbuf + B_ELEMS;
    float*  Qmb  = Qbuf + Q_ELEMS;
    float*  hsb  = Qmb + QM_ELEMS;
    int*    seg  = (int*)(hsb + HS_ELEMS);

    static const float SILU_C_F = (float)silu_c_host();

    prep1<<<NB_K1, 256, 0, stream>>>(emb_z, emb_mol, W2, W1, batch,
                                     pos, xz, mol, Qbuf, Qmb, hsb, seg, aux, SILU_C_F);
    build_AB2<<<NB_K2, 256, 0, stream>>>(Qbuf, Qmb, hsb, Abuf, Bbuf);
    seg_mean<<<G_SEG, 1024, 0, stream>>>(aux, seg, Abuf, Bbuf, out);
}

// Round 17
// 33.620 us; speedup vs baseline: 1.1046x; 1.0233x over previous
//
#include <hip/hip_runtime.h>
#include <math.h>

#define N_NODES 65536
#define G_SEG   512
#define NE      256                  // L-grid intervals over [0,10] for xw lerp

// K1 roles
#define NB_HS 33                     // hs table 257x32
#define NB_Q  128                    // Q[z][m][j]: block = (m, z-quarter)
#define NB_QM 32                     // Qm[mo][m][j]: block = m
#define NB_S  3                      // seg bounds
#define NB_P0 (N_NODES / 256)        // 256: per-node aux
#define NB_K1 (NB_HS + NB_Q + NB_QM + NB_S + NB_P0)   // 452

// K2 roles
#define NB_A  1700                   // 17 e-tiles x 100 z
#define NB_B2 257                    // B rows
#define NB_K2 (NB_A + NB_B2)

#define A_ELEMS  (100 * 257 * 64)    // A[z][e][j], 6.58 MB (lerp pair 256B apart)
#define B_ELEMS  (3 * 257 * 64)      // B[mo][e][j]
#define Q_ELEMS  (100 * 32 * 64)     // 800 KB
#define QM_ELEMS (3 * 32 * 64)
#define HS_ELEMS (257 * 32)

// ---------------------------------------------------------------------------
// K1: five independent light roles.  (exact round-14 code)
// ---------------------------------------------------------------------------
__global__ __launch_bounds__(256) void prep1(
    const float* __restrict__ emb_z, const float* __restrict__ emb_mol,
    const float* __restrict__ W2, const float* __restrict__ W1,
    const int* __restrict__ batch,
    const float* __restrict__ pos, const int* __restrict__ xz,
    const int* __restrict__ mol,
    float* __restrict__ Q, float* __restrict__ Qm, float* __restrict__ hs,
    int* __restrict__ seg, float4* __restrict__ aux, float silu_c)
{
    __shared__ float w2s[64 * 49];   // [cc][u], stride 49 kills bank conflicts
    __shared__ float ezq[1200];      // 25 z x 48 u

    const int b = blockIdx.x;
    const int t = threadIdx.x;

    if (b < NB_HS) {
        const int tid = b * 256 + t;
        if (tid >= HS_ELEMS) return;
        const int e = tid >> 5, m = tid & 31;
        const float L = (float)e * (10.f / (float)NE);
        const float c = 8.4335412f;     // 1.14136 * exp(2)
        float p = 0.f;
#pragma unroll
        for (int k = 0; k < 10; ++k) {
            const float a  = 1.1f * L - (float)k;
            const float bb = (float)(k + 2) - 1.1f * L;
            // exp(-1/a)*exp(-1/b) = exp(-2/(ab)) since a+b == 2
            const float bas = (a > 0.f && bb > 0.f) ? c * __expf(-2.f / (a * bb)) : 0.f;
            p = fmaf(bas, W1[k * 32 + m], p);
        }
        const float scale = 0.02209708691207961f;   // 1/sqrt(2048), folded here
        hs[tid] = scale * silu_c * p / (1.f + __expf(-p));
    } else if (b < NB_HS + NB_Q) {
        const int q  = b - NB_HS;
        const int m  = q >> 2;
        const int zq = q & 3;
        for (int p = t; p < 3072; p += 256) {
            const int l = p / 768, r = p - l * 768;       // r = u*16+wi, u<48
            w2s[((l * 16) + (r & 15)) * 49 + (r >> 4)] = W2[m * 4096 + l * 1024 + r];
        }
        for (int p = t; p < 1200; p += 256) ezq[p] = emb_z[zq * 1200 + p];
        __syncthreads();

        const int zg = t >> 6, cc = t & 63;
#pragma unroll
        for (int zi = 0; zi < 7; ++zi) {
            const int zl = zg + 4 * zi;                   // wave-uniform
            if (zl < 25) {
                float a0 = 0.f, a1 = 0.f, a2 = 0.f, a3 = 0.f;
#pragma unroll
                for (int u = 0; u < 48; u += 4) {
                    a0 = fmaf(ezq[zl * 48 + u + 0], w2s[cc * 49 + u + 0], a0);
                    a1 = fmaf(ezq[zl * 48 + u + 1], w2s[cc * 49 + u + 1], a1);
                    a2 = fmaf(ezq[zl * 48 + u + 2], w2s[cc * 49 + u + 2], a2);
                    a3 = fmaf(ezq[zl * 48 + u + 3], w2s[cc * 49 + u + 3], a3);
                }
                Q[(((zq * 25 + zl) * 32 + m) << 6) + cc] = (a0 + a1) + (a2 + a3);
            }
        }
    } else if (b < NB_HS + NB_Q + NB_QM) {
        const int m = b - (NB_HS + NB_Q);
        if (t < 192) {
            const int mo = t >> 6, j = t & 63;
            const float* wp = W2 + m * 4096 + (j >> 4) * 1024 + 768 + (j & 15);
            float acc = 0.f;
#pragma unroll
            for (int v = 0; v < 16; ++v)
                acc = fmaf(emb_mol[mo * 16 + v], wp[v * 16], acc);
            Qm[((mo * 32 + m) << 6) + j] = acc;
        }
    } else if (b < NB_HS + NB_Q + NB_QM + NB_S) {
        const int g = (b - NB_HS - NB_Q - NB_QM) * 256 + t;
        if (g > G_SEG) return;
        int lo = 0, hi = N_NODES;
        while (lo < hi) {
            const int mid = (lo + hi) >> 1;
            if (batch[mid] < g) lo = mid + 1; else hi = mid;
        }
        seg[g] = lo;
    } else {
        const int i = (b - NB_HS - NB_Q - NB_QM - NB_S) * 256 + t;
        const float px = pos[3 * i], py = pos[3 * i + 1], pz = pos[3 * i + 2];
        const int z  = xz[i];
        const int mo = mol[i];
        const float Lsq = px * px + py * py + pz * pz;
        const float rinv = __builtin_amdgcn_rsqf(Lsq);
        const float L = Lsq * rinv;
        const float tt = fminf(L * ((float)NE / 10.0f), 255.999f);
        const int e = (int)tt;
        const int fr15 = min((int)((tt - (float)e) * 32768.f), 32767);
        float4 a;
        a.x = px * rinv; a.y = py * rinv; a.z = pz * rinv;
        a.w = __uint_as_float(((unsigned)e << 24) | ((unsigned)z << 17) |
                              ((unsigned)mo << 15) | (unsigned)fr15);
        aux[i] = a;
    }
}

// ---------------------------------------------------------------------------
// K2: A[z][e][j] = sum_m hs[e][m] * Q[z][m][j]  (e-inner layout: the lerp
// pair (e, e+1) is 256 B apart -> adjacent cache lines in K3).
// B[mo][e][j] likewise.  (otherwise exact round-14 code)
// ---------------------------------------------------------------------------
__global__ __launch_bounds__(256) void build_AB2(
    const float* __restrict__ Q, const float* __restrict__ Qm,
    const float* __restrict__ hs,
    float* __restrict__ A, float* __restrict__ B)
{
    const int b = blockIdx.x;
    const int t = threadIdx.x;
    const int j = t & 63;
    const int er = __builtin_amdgcn_readfirstlane(t >> 6);

    if (b < NB_A) {
        const int et = b / 100;
        const int z  = b - et * 100;
        float Qr[32];
        const float* Qp = Q + ((z * 32) << 6) + j;
#pragma unroll
        for (int m = 0; m < 32; ++m) Qr[m] = Qp[m << 6];

        const int e0 = et * 16;
#pragma unroll
        for (int p4 = 0; p4 < 4; ++p4) {
            const int e = e0 + er + 4 * p4;               // wave-uniform
            if (e < 257) {
                const float* hp = hs + e * 32;
                float a0 = 0.f, a1 = 0.f, a2 = 0.f, a3 = 0.f;
#pragma unroll
                for (int m = 0; m < 32; m += 4) {
                    a0 = fmaf(hp[m + 0], Qr[m + 0], a0);
                    a1 = fmaf(hp[m + 1], Qr[m + 1], a1);
                    a2 = fmaf(hp[m + 2], Qr[m + 2], a2);
                    a3 = fmaf(hp[m + 3], Qr[m + 3], a3);
                }
                A[((z * 257 + e) << 6) + j] = (a0 + a1) + (a2 + a3);
            }
        }
    } else {
        const int e  = b - NB_A;
        const int mo = t >> 6;
        if (mo < 3) {
            const float* Qp = Qm + ((mo * 32) << 6) + j;
            const float* hp = hs + e * 32;
            float acc = 0.f;
#pragma unroll
            for (int m = 0; m < 32; ++m)
                acc = fmaf(hp[m], Qp[m << 6], acc);
            B[((mo * 257 + e) << 6) + j] = acc;
        }
    }
}

// ---------------------------------------------------------------------------
// K3: exact round-14 seg_mean, with [z][e][j]/[mo][e][j] addressing: the
// f1 endpoint is Ar[64]/Br[64] (adjacent line) instead of 25.6 KB away.
// One block per segment, 1024 thr = 16 waves; wave = (qt, l); direct mean.
// ---------------------------------------------------------------------------
__global__ __launch_bounds__(1024) void seg_mean(
    const float4* __restrict__ aux, const int* __restrict__ seg,
    const float* __restrict__ A, const float* __restrict__ B,
    float* __restrict__ out)
{
    __shared__ float red[16 * 257];

    const int g  = blockIdx.x;
    const int s0 = seg[g], s1 = seg[g + 1];
    const int cnt = s1 - s0;

    const int w16  = __builtin_amdgcn_readfirstlane(threadIdx.x >> 6);  // 0..15
    const int l    = w16 & 3;
    const int qt   = w16 >> 2;
    const int lane = threadIdx.x & 63;
    const int ns   = lane >> 4;
    const int wi   = lane & 15;
    const int jj   = l * 16 + wi;

    const int q0 = s0 + ((cnt * qt) >> 2);
    const int q1 = s0 + ((cnt * (qt + 1)) >> 2);

    float acc[7];
#pragma unroll
    for (int k = 0; k < 7; ++k) acc[k] = 0.f;

    const int niter = (q1 - q0 + 3) >> 2;   // wave-uniform

    float4 aN = make_float4(0.f, 0.f, 1.f, __uint_as_float(0u));
    float a0N = 0.f, a1N = 0.f, b0N = 0.f, b1N = 0.f;
    if (niter > 0) {
        const int ic = min(q0 + ns, q1 - 1);
        aN = aux[ic];
        const unsigned cd = __float_as_uint(aN.w);
        const float* Ar = A + ((((cd >> 17) & 127u) * 257 + (cd >> 24)) << 6) + jj;
        const float* Br = B + ((((cd >> 15) & 3u) * 257 + (cd >> 24)) << 6) + jj;
        a0N = Ar[0]; a1N = Ar[64]; b0N = Br[0]; b1N = Br[64];
    }

    for (int it = 0; it < niter; ++it) {
        const float4 a = aN;
        const float f0 = a0N + b0N, f1 = a1N + b1N;
        const unsigned code = __float_as_uint(a.w);
        const int i = q0 + it * 4 + ns;
        const bool valid = (i < q1);

        if (it + 1 < niter) {
            const int ic = min(q0 + (it + 1) * 4 + ns, q1 - 1);
            aN = aux[ic];
            const unsigned cn = __float_as_uint(aN.w);
            const float* Ar = A + ((((cn >> 17) & 127u) * 257 + (cn >> 24)) << 6) + jj;
            const float* Br = B + ((((cn >> 15) & 3u) * 257 + (cn >> 24)) << 6) + jj;
            a0N = Ar[0]; a1N = Ar[64]; b0N = Br[0]; b1N = Br[64];
        }

        const float fr = (float)(code & 32767u) * 3.0517578125e-5f;  // /32768
        float xwv = fmaf(fr, f1 - f0, f0);
        xwv = valid ? xwv : 0.f;

        const float ux = a.x, uy = a.y, uz = a.z;
        const float s3 = 1.7320508075688772f, s5 = 2.2360679774997896f, s7 = 2.6457513110645907f;

        if (l == 0) {
            acc[0] += xwv;
        } else if (l == 1) {
            acc[0] = fmaf(xwv, s3 * ux, acc[0]);
            acc[1] = fmaf(xwv, s3 * uy, acc[1]);
            acc[2] = fmaf(xwv, s3 * uz, acc[2]);
        } else if (l == 2) {
            const float y2 = uy * uy, x2z2 = ux * ux + uz * uz;
            const float s20 = s3 * ux * uz;
            const float s21 = s3 * ux * uy;
            const float s22 = y2 - 0.5f * x2z2;
            const float s23 = s3 * uy * uz;
            const float s24 = 0.5f * s3 * (uz * uz - ux * ux);
            const float xs = xwv * s5;
            acc[0] = fmaf(xs, s20, acc[0]);
            acc[1] = fmaf(xs, s21, acc[1]);
            acc[2] = fmaf(xs, s22, acc[2]);
            acc[3] = fmaf(xs, s23, acc[3]);
            acc[4] = fmaf(xs, s24, acc[4]);
        } else {
            const float y2 = uy * uy, x2z2 = ux * ux + uz * uz;
            const float s20 = s3 * ux * uz;
            const float s24 = 0.5f * s3 * (uz * uz - ux * ux);
            const float c56 = 0.9128709291752769f;  // sqrt(5/6)
            const float c38 = 0.6123724356957945f;  // sqrt(3/8)
            const float r4 = 4.f * y2 - x2z2;
            const float s30 = c56 * (s20 * uz + s24 * ux);
            const float s31 = s5 * s20 * uy;
            const float s32 = c38 * r4 * ux;
            const float s33 = 0.5f * uy * (2.f * y2 - 3.f * x2z2);
            const float s34 = c38 * uz * r4;
            const float s35 = s5 * s24 * uy;
            const float s36 = c56 * (s24 * uz - s20 * ux);
            const float xs = xwv * s7;
            acc[0] = fmaf(xs, s30, acc[0]);
            acc[1] = fmaf(xs, s31, acc[1]);
            acc[2] = fmaf(xs, s32, acc[2]);
            acc[3] = fmaf(xs, s33, acc[3]);
            acc[4] = fmaf(xs, s34, acc[4]);
            acc[5] = fmaf(xs, s35, acc[5]);
            acc[6] = fmaf(xs, s36, acc[6]);
        }
    }

    const int nl = 2 * l + 1;
    const int off = (l == 0 ? 0 : (l == 1 ? 16 : (l == 2 ? 64 : 144)));
    const int base = off + wi * nl;
#pragma unroll
    for (int k = 0; k < 7; ++k)
        if (k < nl) red[(qt * 4 + ns) * 257 + base + k] = acc[k];
    __syncthreads();

    if (threadIdx.x < 256) {
        float s = 0.f;
#pragma unroll
        for (int ww = 0; ww < 16; ++ww) s += red[ww * 257 + threadIdx.x];
        out[g * 256 + threadIdx.x] = s / (float)max(cnt, 1);
    }
}

// ---------------------------------------------------------------------------
static double silu_c_host()
{
    const int n = 200001;
    const double h = 24.0 / 200000.0;
    double sum = 0.0, prev = 0.0;
    for (int i = 0; i < n; ++i) {
        const double z = -12.0 + h * (double)i;
        const double pdf = exp(-0.5 * z * z) * 0.3989422804014327;
        const double s = z / (1.0 + exp(-z));
        const double f = s * s * pdf;
        if (i) sum += prev + f;
        prev = f;
    }
    sum *= 0.5 * h;
    return 1.0 / sqrt(sum);
}

extern "C" void kernel_launch(void* const* d_in, const int* in_sizes, int n_in,
                              void* d_out, int out_size, void* d_ws, size_t ws_size,
                              hipStream_t stream)
{
    const float* pos     = (const float*)d_in[0];
    const int*   xz      = (const int*)d_in[1];
    const int*   mol     = (const int*)d_in[2];
    const int*   batch   = (const int*)d_in[3];
    const float* emb_z   = (const float*)d_in[4];
    const float* emb_mol = (const float*)d_in[5];
    const float* W1      = (const float*)d_in[6];
    const float* W2      = (const float*)d_in[7];
    float* out = (float*)d_out;

    // workspace (floats): aux | A | B | Q | Qm | hs | seg  ~= 8.7 MB
    float4* aux  = (float4*)d_ws;
    float*  Abuf = (float*)d_ws + 4 * N_NODES;
    float*  Bbuf = Abuf + A_ELEMS;
    float*  Qbuf = Bbuf + B_ELEMS;
    float*  Qmb  = Qbuf + Q_ELEMS;
    float*  hsb  = Qmb + QM_ELEMS;
    int*    seg  = (int*)(hsb + HS_ELEMS);

    static const float SILU_C_F = (float)silu_c_host();

    prep1<<<NB_K1, 256, 0, stream>>>(emb_z, emb_mol, W2, W1, batch,
                                     pos, xz, mol, Qbuf, Qmb, hsb, seg, aux, SILU_C_F);
    build_AB2<<<NB_K2, 256, 0, stream>>>(Qbuf, Qmb, hsb, Abuf, Bbuf);
    seg_mean<<<G_SEG, 1024, 0, stream>>>(aux, seg, Abuf, Bbuf, out);
}